// Round 5
// baseline (226.510 us; speedup 1.0000x reference)
//
#include <hip/hip_runtime.h>

typedef __attribute__((ext_vector_type(4))) float f32x4;
typedef __attribute__((ext_vector_type(8))) short short8;
typedef unsigned short ushort_t;
typedef unsigned int uint_t;

#define R_  32768
#define E_  192
#define V_  96
#define L_  6
#define EPS_ 1e-5f

#define NCHUNK 24
#define NT 144              // L_ * NCHUNK
#define CH_US 12288         // ushorts per chunk: 12 w1 frags + 12 w2 frags, 512 us each
#define CH_BYTES 24576
#define W2_OFF 12288        // byte offset of w2 fragment region within a chunk
#define PP_F 1792           // floats per layer param block (= 7168 bytes)

__device__ __forceinline__ ushort_t f2bf(float f) {
    uint_t i = __builtin_bit_cast(uint_t, f);
    uint_t r = (i + 0x7fffu + ((i >> 16) & 1u)) >> 16;   // RNE
    return (ushort_t)r;
}
// packed f32 pair -> bf16x2 dword (RNE), single HW instr
__device__ __forceinline__ uint_t cvtpk(float a, float b) {
    uint_t r;
    asm("v_cvt_pk_bf16_f32 %0, %1, %2" : "=v"(r) : "v"(a), "v"(b));
    return r;
}

// async global->LDS DMA, 16B per lane: LDS dest = wave-uniform base + lane*16
typedef __attribute__((address_space(1))) const uint_t as1_uint;
typedef __attribute__((address_space(3))) uint_t as3_uint;
__device__ __forceinline__ void glds16(const void* g, void* l) {
    __builtin_amdgcn_global_load_lds((as1_uint*)g, (as3_uint*)l, 16, 0, 0);
}
// 2 waves cover one 24 KiB chunk: each wave stages 12 KiB (12 x 1 KiB issues)
__device__ __forceinline__ void stage12(const char* gchunk, char* lbuf, int w, int lane) {
    const char* g = gchunk + w * 12288 + lane * 16;
    char* l = lbuf + w * 12288;
#pragma unroll
    for (int i = 0; i < 12; ++i) glds16(g + i * 1024, l + i * 1024);
}
// single wave stages a 7 KiB param block
__device__ __forceinline__ void stagep(const char* gsrc, char* lbuf, int lane) {
    const char* g = gsrc + lane * 16;
#pragma unroll
    for (int i = 0; i < 7; ++i) glds16(g + i * 1024, lbuf + i * 1024);
}

// ---- LayerNorm on D-layout register state (one 16-row group) ----
// lane(g,c) holds x[e = et*16 + g*4 + r][row=c] in a[et][r]; reduce across g (xor 16,32)
__device__ __forceinline__ void lnD(f32x4 (&a)[12], const float* gp, const float* bp, int g) {
    float s = 0.f, sq = 0.f;
#pragma unroll
    for (int et = 0; et < 12; ++et)
#pragma unroll
        for (int r = 0; r < 4; ++r) { float x = a[et][r]; s += x; sq += x * x; }
    s += __shfl_xor(s, 16); sq += __shfl_xor(sq, 16);
    s += __shfl_xor(s, 32); sq += __shfl_xor(sq, 32);
    float mu = s * (1.f / 192.f);
    float ri = rsqrtf(sq * (1.f / 192.f) - mu * mu + EPS_);
#pragma unroll
    for (int et = 0; et < 12; ++et) {
        float4 gg = *(const float4*)(gp + et * 16 + g * 4);
        float4 bb = *(const float4*)(bp + et * 16 + g * 4);
        a[et][0] = (a[et][0] - mu) * ri * gg.x + bb.x;
        a[et][1] = (a[et][1] - mu) * ri * gg.y + bb.y;
        a[et][2] = (a[et][2] - mu) * ri * gg.z + bb.z;
        a[et][3] = (a[et][3] - mu) * ri * gg.w + bb.w;
    }
}

// ---- pack D-layout f32 state to bf16 and exchange into B-fragments ----
__device__ __forceinline__ void packex(const f32x4 (&a)[12], int lane, short8 (&xf)[6]) {
    uint_t pk[12][2];
#pragma unroll
    for (int et = 0; et < 12; ++et) {
        pk[et][0] = cvtpk(a[et][0], a[et][1]);
        pk[et][1] = cvtpk(a[et][2], a[et][3]);
    }
    const bool hi = (lane & 32) != 0;
    const int base = ((lane & 16) << 1) + (lane & 15);
#pragma unroll
    for (int kc = 0; kc < 6; ++kc) {
        uint_t dw[4];
#pragma unroll
        for (int d = 0; d < 4; ++d) {
            int src = base + (d >> 1) * 16;
            uint_t A = (uint_t)__shfl((int)pk[2 * kc][d & 1], src);
            uint_t B = (uint_t)__shfl((int)pk[2 * kc + 1][d & 1], src);
            dw[d] = hi ? B : A;
        }
        uint4 q; q.x = dw[0]; q.y = dw[1]; q.z = dw[2]; q.w = dw[3];
        xf[kc] = __builtin_bit_cast(short8, q);
    }
}

// ---------------- weight/param convert: fragment-ordered chunks ----------------
__global__ void wconv_k(const float* __restrict__ W1, const float* __restrict__ W2,
                        const float* __restrict__ Wf,
                        const float* __restrict__ g1, const float* __restrict__ b1n,
                        const float* __restrict__ g2, const float* __restrict__ b2n,
                        const float* __restrict__ bb1, const float* __restrict__ bb2,
                        ushort_t* __restrict__ wch, ushort_t* __restrict__ wfr,
                        float* __restrict__ pp)
{
    int i = blockIdx.x * 256 + threadIdx.x;
    const int NW = 884736;
    if (i < NW) {   // w1 fragments: chunk t, block (kc*2+fi), lane li, elem j
        int t = i / 6144, wc = i % 6144;
        int blk = wc >> 9, li = (wc >> 3) & 63, j = wc & 7;
        int kc = blk >> 1, fi = blk & 1, g = li >> 4, c = li & 15;
        int cc = t % 24, lyr = t / 24;
        int e = kc * 32 + g * 8 + j, f = cc * 32 + fi * 16 + c;
        wch[(size_t)t * CH_US + wc] = f2bf(W1[((size_t)lyr * 192 + e) * 768 + f]);
        return;
    }
    i -= NW;
    if (i < NW) {   // w2 fragments: block et, lane li, elem j
        int t = i / 6144, wc = i % 6144;
        int et = wc >> 9, li = (wc >> 3) & 63, j = wc & 7;
        int g = li >> 4, c = li & 15;
        int cc = t % 24, lyr = t / 24;
        wch[(size_t)t * CH_US + 6144 + wc] =
            f2bf(W2[((size_t)lyr * 768 + cc * 32 + g * 8 + j) * 192 + et * 16 + c]);
        return;
    }
    i -= NW;
    if (i < 36 * 512) {   // head fragments: block (kc*6+vt)
        int blk = i >> 9, li = (i >> 3) & 63, j = i & 7;
        int kc = blk / 6, vt = blk % 6, g = li >> 4, c = li & 15;
        wfr[i] = f2bf(Wf[((size_t)kc * 32 + g * 8 + j) * 96 + vt * 16 + c]);
        return;
    }
    i -= 36 * 512;
    if (i < L_ * PP_F) {
        int l = i / PP_F, j = i % PP_F;
        float val = 0.f;
        if      (j < 192)  val = g1 [l * 192 + j];
        else if (j < 384)  val = b1n[l * 192 + j - 192];
        else if (j < 576)  val = g2 [l * 192 + j - 384];
        else if (j < 768)  val = b2n[l * 192 + j - 576];
        else if (j < 1536) val = bb1[l * 768 + j - 768];
        else if (j < 1728) val = bb2[l * 192 + j - 1536];
        pp[(size_t)l * PP_F + j] = val;
    }
}

// ---------------- the whole network, one kernel, 64 rows/block (32/wave) ----------------
__global__ __launch_bounds__(128, 1) void net_k(
    const int* __restrict__ idxp, const int* __restrict__ tgp,
    const float* __restrict__ tok, const float* __restrict__ pos,
    const float* __restrict__ fng, const float* __restrict__ fnb,
    const float* __restrict__ bfb,
    const ushort_t* __restrict__ wch, const ushort_t* __restrict__ wfr,
    const float* __restrict__ pp,
    float* __restrict__ pred, float* __restrict__ partial)
{
    __shared__ __align__(16) ushort_t wlds[2][CH_US];
    __shared__ __align__(16) float plds[2][PP_F];
    __shared__ float lsred[2];

    const int tid = threadIdx.x, lane = tid & 63, w = tid >> 6;
    const int c = lane & 15, g = lane >> 4;
    // wave holds 32 rows: rj*16 + c within the wave's row window
    const int row0 = blockIdx.x * 64 + w * 32;

    // prologue staging: weight chunk 0 (both waves) + layer-0 params (wave 0)
    stage12((const char*)wch, (char*)&wlds[0][0], w, lane);
    if (w == 0) stagep((const char*)pp, (char*)&plds[0][0], lane);

    // embedding in D-layout: axT[rj][et][r] = x[e=et*16+g*4+r][row0+rj*16+c]
    f32x4 axT[2][12];
#pragma unroll
    for (int rj = 0; rj < 2; ++rj) {
        int row = row0 + rj * 16 + c;
        int id = idxp[row];
        int tt = row & 127;
#pragma unroll
        for (int et = 0; et < 12; ++et) {
            float4 a = *(const float4*)(tok + (size_t)id * 192 + et * 16 + g * 4);
            float4 b = *(const float4*)(pos + (size_t)tt * 192 + et * 16 + g * 4);
            axT[rj][et][0] = a.x + b.x; axT[rj][et][1] = a.y + b.y;
            axT[rj][et][2] = a.z + b.z; axT[rj][et][3] = a.w + b.w;
        }
    }
    __syncthreads();

    const bool hi = (lane & 32) != 0;
    const int xbase = ((lane & 16) << 1) + (lane & 15);

    int cur = 0, pcur = 0;
#pragma unroll 1
    for (int l = 0; l < L_; ++l) {
        short8 xf[2][6];
#pragma unroll
        for (int rj = 0; rj < 2; ++rj) {
            lnD(axT[rj], &plds[pcur][0],   &plds[pcur][192], g);
            lnD(axT[rj], &plds[pcur][384], &plds[pcur][576], g);
            packex(axT[rj], lane, xf[rj]);
#pragma unroll
            for (int et = 0; et < 12; ++et)
                { axT[rj][et][0] = 0.f; axT[rj][et][1] = 0.f; axT[rj][et][2] = 0.f; axT[rj][et][3] = 0.f; }
        }

#pragma unroll 1
        for (int cc = 0; cc < NCHUNK; ++cc) {
            const int t = l * NCHUNK + cc;
            if (t + 1 < NT)
                stage12((const char*)wch + (size_t)(t + 1) * CH_BYTES, (char*)&wlds[cur ^ 1][0], w, lane);
            if (cc == NCHUNK - 1 && l + 1 < L_ && w == 0)
                stagep((const char*)pp + (size_t)(l + 1) * (PP_F * 4), (char*)&plds[pcur ^ 1][0], lane);

            const char* wb = (const char*)&wlds[cur][0] + lane * 16;
            // hoist ALL weight-fragment LDS reads: saturate DS pipe early,
            // MFMA/VALU overlap the tail (1 wave/SIMD: VGPR budget is 512)
            uint4 wa[12], w2r[12];
#pragma unroll
            for (int q = 0; q < 12; ++q) wa[q] = *(const uint4*)(wb + q * 1024);
#pragma unroll
            for (int et = 0; et < 12; ++et) w2r[et] = *(const uint4*)(wb + W2_OFF + et * 1024);

            // gemm1 (swapped): hT = W1chunk x x, both row groups
            f32x4 ah[2][2];     // [fi][rj]
            ah[0][0] = f32x4{}; ah[0][1] = f32x4{}; ah[1][0] = f32x4{}; ah[1][1] = f32x4{};
            __builtin_amdgcn_s_setprio(1);
#pragma unroll
            for (int kc = 0; kc < 6; ++kc) {
                short8 a0 = __builtin_bit_cast(short8, wa[kc * 2]);
                short8 a1 = __builtin_bit_cast(short8, wa[kc * 2 + 1]);
                ah[0][0] = __builtin_amdgcn_mfma_f32_16x16x32_bf16(a0, xf[0][kc], ah[0][0], 0, 0, 0);
                ah[0][1] = __builtin_amdgcn_mfma_f32_16x16x32_bf16(a0, xf[1][kc], ah[0][1], 0, 0, 0);
                ah[1][0] = __builtin_amdgcn_mfma_f32_16x16x32_bf16(a1, xf[0][kc], ah[1][0], 0, 0, 0);
                ah[1][1] = __builtin_amdgcn_mfma_f32_16x16x32_bf16(a1, xf[1][kc], ah[1][1], 0, 0, 0);
            }
            __builtin_amdgcn_s_setprio(0);

            // bias1 + relu in D-layout, pack, exchange packed dwords -> hb[rj]
            float4 b1a = *(const float4*)(&plds[pcur][768 + cc * 32 + g * 4]);
            float4 b1b = *(const float4*)(&plds[pcur][768 + cc * 32 + 16 + g * 4]);
            short8 hb[2];
#pragma unroll
            for (int rj = 0; rj < 2; ++rj) {
                float y00 = fmaxf(ah[0][rj][0] + b1a.x, 0.f), y01 = fmaxf(ah[0][rj][1] + b1a.y, 0.f);
                float y02 = fmaxf(ah[0][rj][2] + b1a.z, 0.f), y03 = fmaxf(ah[0][rj][3] + b1a.w, 0.f);
                float y10 = fmaxf(ah[1][rj][0] + b1b.x, 0.f), y11 = fmaxf(ah[1][rj][1] + b1b.y, 0.f);
                float y12 = fmaxf(ah[1][rj][2] + b1b.z, 0.f), y13 = fmaxf(ah[1][rj][3] + b1b.w, 0.f);
                uint_t pA0 = cvtpk(y00, y01), pA1 = cvtpk(y02, y03);
                uint_t pB0 = cvtpk(y10, y11), pB1 = cvtpk(y12, y13);
                uint_t dw[4];
#pragma unroll
                for (int d = 0; d < 4; ++d) {
                    int src = xbase + (d >> 1) * 16;
                    uint_t A = (uint_t)__shfl((int)((d & 1) ? pA1 : pA0), src);
                    uint_t B = (uint_t)__shfl((int)((d & 1) ? pB1 : pB0), src);
                    dw[d] = hi ? B : A;
                }
                uint4 hq; hq.x = dw[0]; hq.y = dw[1]; hq.z = dw[2]; hq.w = dw[3];
                hb[rj] = __builtin_bit_cast(short8, hq);
            }

            // gemm2 (swapped): xT += W2chunk x h, both row groups
            __builtin_amdgcn_s_setprio(1);
#pragma unroll
            for (int et = 0; et < 12; ++et) {
                short8 wq = __builtin_bit_cast(short8, w2r[et]);
                axT[0][et] = __builtin_amdgcn_mfma_f32_16x16x32_bf16(wq, hb[0], axT[0][et], 0, 0, 0);
                axT[1][et] = __builtin_amdgcn_mfma_f32_16x16x32_bf16(wq, hb[1], axT[1][et], 0, 0, 0);
            }
            __builtin_amdgcn_s_setprio(0);

            __syncthreads();     // drains glds vmcnt, flips double buffer
            cur ^= 1;
        }

        // + bias2 (still D-layout)
#pragma unroll
        for (int et = 0; et < 12; ++et) {
            float4 bb = *(const float4*)(&plds[pcur][1536 + et * 16 + g * 4]);
#pragma unroll
            for (int rj = 0; rj < 2; ++rj) {
                axT[rj][et][0] += bb.x; axT[rj][et][1] += bb.y;
                axT[rj][et][2] += bb.z; axT[rj][et][3] += bb.w;
            }
        }
        pcur ^= 1;
    }

    // ---- final LN + head ----
    float lsum = 0.f;
#pragma unroll
    for (int rj = 0; rj < 2; ++rj) {
        lnD(axT[rj], fng, fnb, g);
        short8 xf[6];
        packex(axT[rj], lane, xf);
        f32x4 av[6] = {};
        __builtin_amdgcn_s_setprio(1);
#pragma unroll
        for (int kc = 0; kc < 6; ++kc)
#pragma unroll
            for (int vt = 0; vt < 6; ++vt) {
                short8 wf = *(const short8*)(wfr + (size_t)(kc * 6 + vt) * 512 + lane * 8);
                av[vt] = __builtin_amdgcn_mfma_f32_16x16x32_bf16(wf, xf[kc], av[vt], 0, 0, 0);
            }
        __builtin_amdgcn_s_setprio(0);

        float vv[6][4];
#pragma unroll
        for (int vt = 0; vt < 6; ++vt) {
            float4 bb = *(const float4*)(bfb + vt * 16 + g * 4);
            vv[vt][0] = av[vt][0] + bb.x;
            vv[vt][1] = av[vt][1] + bb.y;
            vv[vt][2] = av[vt][2] + bb.z;
            vv[vt][3] = av[vt][3] + bb.w;
        }
        float mx = -1e30f;
#pragma unroll
        for (int vt = 0; vt < 6; ++vt)
#pragma unroll
            for (int r = 0; r < 4; ++r) mx = fmaxf(mx, vv[vt][r]);
        mx = fmaxf(mx, __shfl_xor(mx, 16));
        mx = fmaxf(mx, __shfl_xor(mx, 32));
        float se = 0.f;
#pragma unroll
        for (int vt = 0; vt < 6; ++vt)
#pragma unroll
            for (int r = 0; r < 4; ++r) se += expf(vv[vt][r] - mx);
        se += __shfl_xor(se, 16);
        se += __shfl_xor(se, 32);
        float lse = logf(se) + mx;
        int myrow = row0 + rj * 16 + c;
        int tgt = tgp[myrow];
#pragma unroll
        for (int vt = 0; vt < 6; ++vt)
#pragma unroll
            for (int r = 0; r < 4; ++r)
                if (tgt == vt * 16 + g * 4 + r) lsum += lse - vv[vt][r];
#pragma unroll
        for (int vt = 0; vt < 6; ++vt) {
            float4 o;
            o.x = vv[vt][0]; o.y = vv[vt][1]; o.z = vv[vt][2]; o.w = vv[vt][3];
            *(float4*)(pred + (size_t)myrow * 96 + vt * 16 + g * 4) = o;
        }
    }
#pragma unroll
    for (int m = 1; m < 64; m <<= 1) lsum += __shfl_xor(lsum, m);
    if (lane == 0) lsred[w] = lsum;
    __syncthreads();
    if (tid == 0) partial[blockIdx.x] = lsred[0] + lsred[1];
}

__global__ void lossred_k(const float* __restrict__ partial, float* __restrict__ out)
{
    __shared__ double sd[256];
    int t = threadIdx.x;
    sd[t] = (double)partial[t] + (double)partial[t + 256];
    __syncthreads();
    for (int s = 128; s > 0; s >>= 1) {
        if (t < s) sd[t] += sd[t + s];
        __syncthreads();
    }
    if (t == 0) out[0] = (float)(sd[0] / (double)R_);
}

extern "C" void kernel_launch(void* const* d_in, const int* in_sizes, int n_in,
                              void* d_out, int out_size, void* d_ws, size_t ws_size,
                              hipStream_t stream)
{
    (void)in_sizes; (void)n_in; (void)out_size; (void)ws_size;
    const int*   index   = (const int*)  d_in[0];
    const int*   targets = (const int*)  d_in[1];
    const float* tok     = (const float*)d_in[2];
    const float* pos     = (const float*)d_in[3];
    const float* ln1g    = (const float*)d_in[4];
    const float* ln1b    = (const float*)d_in[5];
    const float* ln2g    = (const float*)d_in[6];
    const float* ln2b    = (const float*)d_in[7];
    // d_in[8..10] = Wq/Wk/Wv: dead in the reference forward
    const float* W1      = (const float*)d_in[11];
    const float* b1      = (const float*)d_in[12];
    const float* W2      = (const float*)d_in[13];
    const float* b2      = (const float*)d_in[14];
    const float* fng     = (const float*)d_in[15];
    const float* fnb     = (const float*)d_in[16];
    const float* Wf      = (const float*)d_in[17];
    const float* bfv     = (const float*)d_in[18];

    ushort_t* wch = (ushort_t*)d_ws;                        // [144][12288] us (24576B chunks)
    ushort_t* wfr = wch + (size_t)NT * CH_US;               // [36][512] head fragments
    float* pp     = (float*)(wfr + 36 * 512);               // [6][1792] f32 (16B-aligned)
    float* partial = pp + (size_t)L_ * PP_F;                // [512]
    float* pred  = (float*)d_out;
    float* lossp = pred + (size_t)R_ * V_;

    const int nconv = 2 * 884736 + 36 * 512 + L_ * PP_F;    // 1798656 = 7026*256
    wconv_k<<<nconv / 256, 256, 0, stream>>>(W1, W2, Wf, ln1g, ln1b, ln2g, ln2b,
                                             b1, b2, wch, wfr, pp);
    net_k<<<512, 128, 0, stream>>>(index, targets, tok, pos, fng, fnb, bfv,
                                   wch, wfr, pp, pred, partial);
    lossred_k<<<1, 256, 0, stream>>>(partial, lossp);
}

// Round 6
// 211.469 us; speedup vs baseline: 1.0711x; 1.0711x over previous
//
#include <hip/hip_runtime.h>

typedef __attribute__((ext_vector_type(4))) float f32x4;
typedef __attribute__((ext_vector_type(8))) short short8;
typedef unsigned short ushort_t;
typedef unsigned int uint_t;

#define R_  32768
#define E_  192
#define V_  96
#define L_  6
#define EPS_ 1e-5f

#define NCHUNK 24
#define NT 144              // L_ * NCHUNK
#define CH_US 12288         // ushorts per chunk: 12 w1 frags + 12 w2 frags, 512 us each
#define CH_BYTES 24576
#define W2_OFF 12288        // byte offset of w2 fragment region within a chunk

__device__ __forceinline__ ushort_t f2bf(float f) {
    uint_t i = __builtin_bit_cast(uint_t, f);
    uint_t r = (i + 0x7fffu + ((i >> 16) & 1u)) >> 16;   // RNE
    return (ushort_t)r;
}
// packed f32 pair -> bf16x2 dword (RNE), single HW instr
__device__ __forceinline__ uint_t cvtpk(float a, float b) {
    uint_t r;
    asm("v_cvt_pk_bf16_f32 %0, %1, %2" : "=v"(r) : "v"(a), "v"(b));
    return r;
}

// async global->LDS DMA, 16B per lane
typedef __attribute__((address_space(1))) const uint_t as1_uint;
typedef __attribute__((address_space(3))) uint_t as3_uint;
__device__ __forceinline__ void glds16(const void* g, void* l) {
    __builtin_amdgcn_global_load_lds((as1_uint*)g, (as3_uint*)l, 16, 0, 0);
}
// 4 waves cover one 12 KiB w1 region: each wave stages 3 KiB
__device__ __forceinline__ void stage3(const char* gchunk, char* lbuf, int w, int lane) {
    const char* g = gchunk + w * 3072 + lane * 16;
    char* l = lbuf + w * 3072;
#pragma unroll
    for (int i = 0; i < 3; ++i) glds16(g + i * 1024, l + i * 1024);
}
// single wave stages a 3 KiB bias1 block
__device__ __forceinline__ void stageb1(const char* gsrc, char* lbuf, int lane) {
    const char* g = gsrc + lane * 16;
#pragma unroll
    for (int i = 0; i < 3; ++i) glds16(g + i * 1024, lbuf + i * 1024);
}
// w2 fragments for chunk t: 12 x 1KiB, global (L1/L2-hot), register-resident
__device__ __forceinline__ void loadw2(uint4 (&d)[12], const ushort_t* wch, int t, int lane) {
    const char* p = (const char*)wch + (size_t)t * CH_BYTES + W2_OFF + lane * 16;
#pragma unroll
    for (int e = 0; e < 12; ++e) d[e] = *(const uint4*)(p + e * 1024);
}

// ---- LayerNorm on D-layout register state ----
__device__ __forceinline__ void lnD(f32x4 (&a)[12], const float* gp, const float* bp, int g) {
    float s = 0.f, sq = 0.f;
#pragma unroll
    for (int et = 0; et < 12; ++et)
#pragma unroll
        for (int r = 0; r < 4; ++r) { float x = a[et][r]; s += x; sq += x * x; }
    s += __shfl_xor(s, 16); sq += __shfl_xor(sq, 16);
    s += __shfl_xor(s, 32); sq += __shfl_xor(sq, 32);
    float mu = s * (1.f / 192.f);
    float ri = rsqrtf(sq * (1.f / 192.f) - mu * mu + EPS_);
#pragma unroll
    for (int et = 0; et < 12; ++et) {
        float4 gg = *(const float4*)(gp + et * 16 + g * 4);
        float4 bb = *(const float4*)(bp + et * 16 + g * 4);
        a[et][0] = (a[et][0] - mu) * ri * gg.x + bb.x;
        a[et][1] = (a[et][1] - mu) * ri * gg.y + bb.y;
        a[et][2] = (a[et][2] - mu) * ri * gg.z + bb.z;
        a[et][3] = (a[et][3] - mu) * ri * gg.w + bb.w;
    }
}

// ---- pack D-layout f32 state to bf16 and exchange into B-fragments ----
__device__ __forceinline__ void packex(const f32x4 (&a)[12], int lane, short8 (&xf)[6]) {
    uint_t pk[12][2];
#pragma unroll
    for (int et = 0; et < 12; ++et) {
        pk[et][0] = cvtpk(a[et][0], a[et][1]);
        pk[et][1] = cvtpk(a[et][2], a[et][3]);
    }
    const bool hi = (lane & 32) != 0;
    const int base = ((lane & 16) << 1) + (lane & 15);
#pragma unroll
    for (int kc = 0; kc < 6; ++kc) {
        uint_t dw[4];
#pragma unroll
        for (int d = 0; d < 4; ++d) {
            int src = base + (d >> 1) * 16;
            uint_t A = (uint_t)__shfl((int)pk[2 * kc][d & 1], src);
            uint_t B = (uint_t)__shfl((int)pk[2 * kc + 1][d & 1], src);
            dw[d] = hi ? B : A;
        }
        uint4 q; q.x = dw[0]; q.y = dw[1]; q.z = dw[2]; q.w = dw[3];
        xf[kc] = __builtin_bit_cast(short8, q);
    }
}

// ---------------- weight convert: fragment-ordered chunks ----------------
__global__ void wconv_k(const float* __restrict__ W1, const float* __restrict__ W2,
                        const float* __restrict__ Wf,
                        ushort_t* __restrict__ wch, ushort_t* __restrict__ wfr)
{
    int i = blockIdx.x * 256 + threadIdx.x;
    const int NW = 884736;
    if (i < NW) {   // w1 fragments: chunk t, block (kc*2+fi), lane li, elem j
        int t = i / 6144, wc = i % 6144;
        int blk = wc >> 9, li = (wc >> 3) & 63, j = wc & 7;
        int kc = blk >> 1, fi = blk & 1, g = li >> 4, c = li & 15;
        int cc = t % 24, lyr = t / 24;
        int e = kc * 32 + g * 8 + j, f = cc * 32 + fi * 16 + c;
        wch[(size_t)t * CH_US + wc] = f2bf(W1[((size_t)lyr * 192 + e) * 768 + f]);
        return;
    }
    i -= NW;
    if (i < NW) {   // w2 fragments: block et, lane li, elem j
        int t = i / 6144, wc = i % 6144;
        int et = wc >> 9, li = (wc >> 3) & 63, j = wc & 7;
        int g = li >> 4, c = li & 15;
        int cc = t % 24, lyr = t / 24;
        wch[(size_t)t * CH_US + 6144 + wc] =
            f2bf(W2[((size_t)lyr * 768 + cc * 32 + g * 8 + j) * 192 + et * 16 + c]);
        return;
    }
    i -= NW;
    if (i < 36 * 512) {   // head fragments: block (kc*6+vt)
        int blk = i >> 9, li = (i >> 3) & 63, j = i & 7;
        int kc = blk / 6, vt = blk % 6, g = li >> 4, c = li & 15;
        wfr[i] = f2bf(Wf[((size_t)kc * 32 + g * 8 + j) * 96 + vt * 16 + c]);
    }
}

// one chunk of the FFN: gemm1 (w1 from LDS) -> bias+relu+exchange -> gemm2 (w2 from regs)
__device__ __forceinline__ void chunk_body(
    int t, int cc, int l, int w, int lane, int g, int& cur,
    const ushort_t* __restrict__ wch, const float* __restrict__ b1g,
    ushort_t (&wlds)[2][CH_US / 2], float (&b1lds)[2][768],
    const short8 (&xf)[6], f32x4 (&axT)[12],
    const uint4 (&w2cur)[12], uint4 (&w2nxt)[12],
    bool hi, int xbase)
{
    const char* wb = (const char*)&wlds[cur][0] + lane * 16;
    uint4 wa[12];
#pragma unroll
    for (int q = 0; q < 12; ++q) wa[q] = *(const uint4*)(wb + q * 1024);

    if (t + 1 < NT) {
        stage3((const char*)wch + (size_t)(t + 1) * CH_BYTES, (char*)&wlds[cur ^ 1][0], w, lane);
        loadw2(w2nxt, wch, t + 1, lane);
    }
    if (cc == 22 && l + 1 < L_ && w == 0)
        stageb1((const char*)(b1g + (l + 1) * 768), (char*)&b1lds[(l + 1) & 1][0], lane);

    // gemm1 (swapped): hT = W1chunk x x
    f32x4 ah0 = {}, ah1 = {};
    __builtin_amdgcn_s_setprio(1);
#pragma unroll
    for (int kc = 0; kc < 6; ++kc) {
        ah0 = __builtin_amdgcn_mfma_f32_16x16x32_bf16(__builtin_bit_cast(short8, wa[kc * 2]),     xf[kc], ah0, 0, 0, 0);
        ah1 = __builtin_amdgcn_mfma_f32_16x16x32_bf16(__builtin_bit_cast(short8, wa[kc * 2 + 1]), xf[kc], ah1, 0, 0, 0);
    }
    __builtin_amdgcn_s_setprio(0);

    // bias1 + relu in D-layout, pack, exchange packed dwords -> hb
    float4 b1a = *(const float4*)(&b1lds[l & 1][cc * 32 + g * 4]);
    float4 b1b = *(const float4*)(&b1lds[l & 1][cc * 32 + 16 + g * 4]);
    float y00 = fmaxf(ah0[0] + b1a.x, 0.f), y01 = fmaxf(ah0[1] + b1a.y, 0.f);
    float y02 = fmaxf(ah0[2] + b1a.z, 0.f), y03 = fmaxf(ah0[3] + b1a.w, 0.f);
    float y10 = fmaxf(ah1[0] + b1b.x, 0.f), y11 = fmaxf(ah1[1] + b1b.y, 0.f);
    float y12 = fmaxf(ah1[2] + b1b.z, 0.f), y13 = fmaxf(ah1[3] + b1b.w, 0.f);
    uint_t pA0 = cvtpk(y00, y01), pA1 = cvtpk(y02, y03);
    uint_t pB0 = cvtpk(y10, y11), pB1 = cvtpk(y12, y13);
    uint_t dw[4];
#pragma unroll
    for (int d = 0; d < 4; ++d) {
        int src = xbase + (d >> 1) * 16;
        uint_t A = (uint_t)__shfl((int)((d & 1) ? pA1 : pA0), src);
        uint_t B = (uint_t)__shfl((int)((d & 1) ? pB1 : pB0), src);
        dw[d] = hi ? B : A;
    }
    uint4 hq; hq.x = dw[0]; hq.y = dw[1]; hq.z = dw[2]; hq.w = dw[3];
    short8 hb = __builtin_bit_cast(short8, hq);

    // gemm2 (swapped): xT += W2chunk x h   (w2 fragments already in registers)
    __builtin_amdgcn_s_setprio(1);
#pragma unroll
    for (int et = 0; et < 12; ++et)
        axT[et] = __builtin_amdgcn_mfma_f32_16x16x32_bf16(__builtin_bit_cast(short8, w2cur[et]), hb, axT[et], 0, 0, 0);
    __builtin_amdgcn_s_setprio(0);

    __syncthreads();     // drains glds vmcnt; w2nxt loads complete here too
    cur ^= 1;
}

// ---------------- the whole network, one kernel, 64 rows/block ----------------
__global__ __launch_bounds__(256, 2) void net_k(
    const int* __restrict__ idxp, const int* __restrict__ tgp,
    const float* __restrict__ tok, const float* __restrict__ pos,
    const float* __restrict__ ln1g, const float* __restrict__ ln1b,
    const float* __restrict__ ln2g, const float* __restrict__ ln2b,
    const float* __restrict__ b1g, const float* __restrict__ b2g,
    const float* __restrict__ fng, const float* __restrict__ fnb,
    const float* __restrict__ bfb,
    const ushort_t* __restrict__ wch, const ushort_t* __restrict__ wfr,
    float* __restrict__ pred, float* __restrict__ partial)
{
    __shared__ __align__(16) ushort_t wlds[2][CH_US / 2];   // w1 only: 2 x 12 KiB
    __shared__ __align__(16) float b1lds[2][768];           // bias1 dbuf: 6 KiB
    __shared__ float lsred[4];

    const int tid = threadIdx.x, lane = tid & 63, w = tid >> 6;
    const int c = lane & 15, g = lane >> 4;
    const int myrow = blockIdx.x * 64 + w * 16 + c;

    // prologue: stage w1 chunk 0 + bias1 layer 0, prefetch w2 chunk 0 into regs
    stage3((const char*)wch, (char*)&wlds[0][0], w, lane);
    if (w == 0) stageb1((const char*)b1g, (char*)&b1lds[0][0], lane);
    uint4 w2A[12], w2B[12];
    loadw2(w2A, wch, 0, lane);

    // embedding in D-layout: lane(g,c) holds x[e=et*16+g*4+r][row c]
    f32x4 axT[12];
    {
        int id = idxp[myrow];
        int tt = myrow & 127;
#pragma unroll
        for (int et = 0; et < 12; ++et) {
            float4 a = *(const float4*)(tok + (size_t)id * 192 + et * 16 + g * 4);
            float4 b = *(const float4*)(pos + (size_t)tt * 192 + et * 16 + g * 4);
            axT[et][0] = a.x + b.x; axT[et][1] = a.y + b.y;
            axT[et][2] = a.z + b.z; axT[et][3] = a.w + b.w;
        }
    }
    __syncthreads();

    const bool hi = (lane & 32) != 0;
    const int xbase = ((lane & 16) << 1) + (lane & 15);

    int cur = 0;
#pragma unroll 1
    for (int l = 0; l < L_; ++l) {
        // n2 = LN2(LN1(x)) on D-layout state (params straight from global/L1)
        lnD(axT, ln1g + l * 192, ln1b + l * 192, g);
        lnD(axT, ln2g + l * 192, ln2b + l * 192, g);
        short8 xf[6];
        packex(axT, lane, xf);
#pragma unroll
        for (int et = 0; et < 12; ++et)
            { axT[et][0] = 0.f; axT[et][1] = 0.f; axT[et][2] = 0.f; axT[et][3] = 0.f; }

#pragma unroll 1
        for (int cc = 0; cc < NCHUNK; cc += 2) {
            const int t = l * NCHUNK + cc;
            chunk_body(t,     cc,     l, w, lane, g, cur, wch, b1g, wlds, b1lds, xf, axT, w2A, w2B, hi, xbase);
            chunk_body(t + 1, cc + 1, l, w, lane, g, cur, wch, b1g, wlds, b1lds, xf, axT, w2B, w2A, hi, xbase);
        }

        // + bias2 (from global, L1-hot)
#pragma unroll
        for (int et = 0; et < 12; ++et) {
            float4 bb = *(const float4*)(b2g + l * 192 + et * 16 + g * 4);
            axT[et][0] += bb.x; axT[et][1] += bb.y; axT[et][2] += bb.z; axT[et][3] += bb.w;
        }
    }

    // ---- final LN + head ----
    lnD(axT, fng, fnb, g);
    short8 xf[6];
    packex(axT, lane, xf);
    f32x4 av[6] = {};
    __builtin_amdgcn_s_setprio(1);
#pragma unroll
    for (int kc = 0; kc < 6; ++kc)
#pragma unroll
        for (int vt = 0; vt < 6; ++vt) {
            short8 wf = *(const short8*)(wfr + (size_t)(kc * 6 + vt) * 512 + lane * 8);
            av[vt] = __builtin_amdgcn_mfma_f32_16x16x32_bf16(wf, xf[kc], av[vt], 0, 0, 0);
        }
    __builtin_amdgcn_s_setprio(0);

    float vv[6][4];
#pragma unroll
    for (int vt = 0; vt < 6; ++vt) {
        float4 bb = *(const float4*)(bfb + vt * 16 + g * 4);
        vv[vt][0] = av[vt][0] + bb.x;
        vv[vt][1] = av[vt][1] + bb.y;
        vv[vt][2] = av[vt][2] + bb.z;
        vv[vt][3] = av[vt][3] + bb.w;
    }
    float mx = -1e30f;
#pragma unroll
    for (int vt = 0; vt < 6; ++vt)
#pragma unroll
        for (int r = 0; r < 4; ++r) mx = fmaxf(mx, vv[vt][r]);
    mx = fmaxf(mx, __shfl_xor(mx, 16));
    mx = fmaxf(mx, __shfl_xor(mx, 32));
    float se = 0.f;
#pragma unroll
    for (int vt = 0; vt < 6; ++vt)
#pragma unroll
        for (int r = 0; r < 4; ++r) se += expf(vv[vt][r] - mx);
    se += __shfl_xor(se, 16);
    se += __shfl_xor(se, 32);
    float lse = logf(se) + mx;
    int tgt = tgp[myrow];
    float lsum = 0.f;
#pragma unroll
    for (int vt = 0; vt < 6; ++vt)
#pragma unroll
        for (int r = 0; r < 4; ++r)
            if (tgt == vt * 16 + g * 4 + r) lsum += lse - vv[vt][r];
#pragma unroll
    for (int vt = 0; vt < 6; ++vt) {
        float4 o;
        o.x = vv[vt][0]; o.y = vv[vt][1]; o.z = vv[vt][2]; o.w = vv[vt][3];
        *(float4*)(pred + (size_t)myrow * 96 + vt * 16 + g * 4) = o;
    }
#pragma unroll
    for (int m = 1; m < 64; m <<= 1) lsum += __shfl_xor(lsum, m);
    if (lane == 0) lsred[w] = lsum;
    __syncthreads();
    if (tid == 0) partial[blockIdx.x] = lsred[0] + lsred[1] + lsred[2] + lsred[3];
}

__global__ void lossred_k(const float* __restrict__ partial, float* __restrict__ out)
{
    __shared__ double sd[256];
    int t = threadIdx.x;
    sd[t] = (double)partial[t] + (double)partial[t + 256];
    __syncthreads();
    for (int s = 128; s > 0; s >>= 1) {
        if (t < s) sd[t] += sd[t + s];
        __syncthreads();
    }
    if (t == 0) out[0] = (float)(sd[0] / (double)R_);
}

extern "C" void kernel_launch(void* const* d_in, const int* in_sizes, int n_in,
                              void* d_out, int out_size, void* d_ws, size_t ws_size,
                              hipStream_t stream)
{
    (void)in_sizes; (void)n_in; (void)out_size; (void)ws_size;
    const int*   index   = (const int*)  d_in[0];
    const int*   targets = (const int*)  d_in[1];
    const float* tok     = (const float*)d_in[2];
    const float* pos     = (const float*)d_in[3];
    const float* ln1g    = (const float*)d_in[4];
    const float* ln1b    = (const float*)d_in[5];
    const float* ln2g    = (const float*)d_in[6];
    const float* ln2b    = (const float*)d_in[7];
    // d_in[8..10] = Wq/Wk/Wv: dead in the reference forward
    const float* W1      = (const float*)d_in[11];
    const float* b1      = (const float*)d_in[12];
    const float* W2      = (const float*)d_in[13];
    const float* b2      = (const float*)d_in[14];
    const float* fng     = (const float*)d_in[15];
    const float* fnb     = (const float*)d_in[16];
    const float* Wf      = (const float*)d_in[17];
    const float* bfv     = (const float*)d_in[18];

    ushort_t* wch = (ushort_t*)d_ws;                        // [144][12288] us (24576B chunks)
    ushort_t* wfr = wch + (size_t)NT * CH_US;               // [36][512] head fragments
    float* partial = (float*)(wfr + 36 * 512);              // [512]
    float* pred  = (float*)d_out;
    float* lossp = pred + (size_t)R_ * V_;

    const int nconv = 2 * 884736 + 36 * 512;                // 1787904 = 6984*256
    wconv_k<<<nconv / 256, 256, 0, stream>>>(W1, W2, Wf, wch, wfr);
    net_k<<<512, 256, 0, stream>>>(index, targets, tok, pos, ln1g, ln1b, ln2g, ln2b,
                                   b1, b2, fng, fnb, bfv, wch, wfr, pred, partial);
    lossred_k<<<1, 256, 0, stream>>>(partial, lossp);
}